// Round 6
// baseline (150.405 us; speedup 1.0000x reference)
//
#include <hip/hip_runtime.h>
#include <hip/hip_bf16.h>

// Conv 3x3, C_IN=128, C_OUT=256, H=W=256, pad=1, stride=1, batch=1.
// R13: xb re-layout [hp][16 ci-chunks][258 w][8 ci] so BOTH prep's xpose write and
//   conv's B-stage are coalesced.
//   R12 post-mortem: cutting LDS fragment reads 40% (DPP rotates) changed conv time
//   by 0.0 us -> LDS reads were never the serial bottleneck; conv plateau ~51 us.
//   Meanwhile total-conv = ~84 us residual: prep's xpose write (consecutive lanes at
//   256 B stride, 16 B each) is 3-4x inflated / DRAM-inefficient -> prep est. ~40 us
//   vs ~11 us ideal (68 MB round trip). New layout makes consecutive lanes write
//   consecutive 16 B units (1 KB/wave-instr). Conv's B-stage in the new layout reads
//   8 contiguous 128 B segments per wave (swizzle math unchanged); Bs LDS layout and
//   the whole verified R12 compute path untouched.

typedef short bf16x8 __attribute__((ext_vector_type(8)));    // 8 bf16 = 4 VGPRs
typedef float f32x4 __attribute__((ext_vector_type(4)));
typedef int   i32x4 __attribute__((ext_vector_type(4)));
typedef unsigned short u16x4 __attribute__((ext_vector_type(4)));
typedef unsigned short u16x8 __attribute__((ext_vector_type(8)));

#define CIN   128
#define COUT  256
#define HH    256
#define WW    256
#define HP    258                 // padded spatial extent
#define CHROW (HP * 8)            // one ci-chunk row: 258 cols x 8 ci = 2064 elems
#define ROWP  (16 * CHROW)        // one padded h row: 16 chunks = 33024 elems

static __device__ __forceinline__ unsigned short f2bf(float v) {
    __hip_bfloat16 b = __float2bfloat16(v);
    return *reinterpret_cast<unsigned short*>(&b);
}

static __device__ __forceinline__ void gload_lds16(const unsigned short* g, unsigned short* l) {
    __builtin_amdgcn_global_load_lds(
        (const __attribute__((address_space(1))) unsigned int*)g,
        (__attribute__((address_space(3))) unsigned int*)l, 16, 0, 0);
}

// DPP rotate within each 16-lane row: row_ror:15 -> lane i <- lane i+1 ; ror:14 -> +2.
template<int CTRL>
static __device__ __forceinline__ bf16x8 rotf(bf16x8 a) {
    i32x4 ai = __builtin_bit_cast(i32x4, a);
    i32x4 r;
    #pragma unroll
    for (int j = 0; j < 4; ++j)
        r[j] = __builtin_amdgcn_mov_dpp(ai[j], CTRL, 0xF, 0xF, true);
    return __builtin_bit_cast(bf16x8, r);
}
#define ROR_P1 0x12F   // row_ror:15  (shift +1 lane)
#define ROR_P2 0x12E   // row_ror:14  (shift +2 lanes)

// ---------------- dispatch 1: fused prepass (edge zero + wreorder + xpose) -----------
// grid: 1024 blocks x 256 threads. xb layout: [hp][c8 0..15][w 0..257][8 ci].
__global__ __launch_bounds__(256) void prep_kernel(const float* __restrict__ x,
                                                   const float* __restrict__ w,
                                                   unsigned short* __restrict__ xb,
                                                   unsigned short* __restrict__ wr) {
    int bid = blockIdx.x;
    int t   = threadIdx.x;

    // (a) edge zeroing: 16448 vec8 tasks
    //   rows hp=0,257 (full): 2 x 4128 contiguous vec8
    //   cols w=0,257 for hp=1..256, c8=0..15: 8192 vec8
    if (bid < 65) {
        int i = bid * 256 + t;
        if (i < 16448) {
            u16x8 z = {0, 0, 0, 0, 0, 0, 0, 0};
            int off;
            if (i < 8256) {
                int r   = (i >= 4128) ? 1 : 0;
                int rem = i - r * 4128;
                off = (r * 257) * ROWP + rem * 8;
            } else {
                int j    = i - 8256;          // 0..8191
                int wsel = j >> 12;           // 0 or 1  -> w = 0 or 257
                int rem  = j & 4095;
                int hp   = (rem >> 4) + 1;    // 1..256
                int c8   = rem & 15;
                off = hp * ROWP + c8 * CHROW + (wsel * 257) * 8;
            }
            *(u16x8*)(&xb[off]) = z;
        }
    }

    // (b) weight reorder: blocks 0..127, one thread per (co,ci), coalesced
    if (bid < 128) {
        int p = bid * 256 + t;    // 0..32767 = co*128+ci
        const float* src = w + p * 9;
        #pragma unroll
        for (int khw = 0; khw < 9; ++khw)
            wr[khw * (COUT * CIN) + p] = f2bf(src[khw]);
    }

    // (c) xpose: NCHW fp32 -> [hp][c8][w][8] bf16, one 64-w tile per block
    int h  = bid >> 2;
    int w0 = (bid & 3) * 64;
    __shared__ unsigned short tile[CIN * 72];   // [ci][w], w padded 64->72

    int wq  = t & 15;          // 16 * float4 = 64 w
    int cib = t >> 4;          // 16 ci per pass
    for (int c0 = 0; c0 < CIN; c0 += 16) {
        int ci = c0 + cib;
        float4 v = *(const float4*)(x + ci * (HH * WW) + h * WW + w0 + wq * 4);
        u16x4 p;
        p.x = f2bf(v.x); p.y = f2bf(v.y); p.z = f2bf(v.z); p.w = f2bf(v.w);
        *(u16x4*)(&tile[ci * 72 + wq * 4]) = p;
    }
    __syncthreads();

    for (int it = 0; it < 4; ++it) {
        int idx = it * 256 + t;       // 0..1023
        int ww_ = idx & 63;           // varies within wave (conflict-free LDS reads,
        int c8  = idx >> 6;           //   and now CONTIGUOUS 16B global writes)
        u16x8 o;
        #pragma unroll
        for (int j = 0; j < 8; ++j)
            o[j] = tile[(c8 * 8 + j) * 72 + ww_];
        int dst = (h + 1) * ROWP + c8 * CHROW + (w0 + ww_ + 1) * 8;
        *(u16x8*)(&xb[dst]) = o;
    }
}

// ---------------- dispatch 2: implicit-GEMM MFMA conv, kw-rotate reuse ---------------
// block tile 256co x 256sp (one output row h), 8 waves of 64co x 128sp, 1 block/CU.
// Identical to R12 except the B-stage global address uses the new xb layout.
__global__ __launch_bounds__(512, 2) void conv_mfma_kernel(const unsigned short* __restrict__ xb,
                                                           const unsigned short* __restrict__ wr,
                                                           const float* __restrict__ bias,
                                                           float* __restrict__ out) {
    __shared__ unsigned short A0[256 * 64];    // 32768 B  (kw=0)
    __shared__ unsigned short A1[256 * 64];    // 32768 B  (kw=1)
    __shared__ unsigned short A2[256 * 64];    // 32768 B  (kw=2)
    __shared__ unsigned short Bs[258 * 64];    // 33024 B  ; total 131328 B

    // XCD-chunked bijective swizzle: 256 blocks, 8 XCDs -> 32 consecutive rows per XCD.
    int bid = blockIdx.x;
    int h   = (bid & 7) * 32 + (bid >> 3);     // 0..255, one output row per block

    int t    = threadIdx.x;     // 0..511
    int lane = t & 63;
    int wave = t >> 6;
    int wm   = wave >> 1;       // co quarter (0..3), 64 co each
    int wn   = wave & 1;        // spatial half (0/1), 128 sp each
    int quad = lane >> 4;
    int l16  = lane & 15;

    f32x4 acc[4][8];
    #pragma unroll
    for (int mi = 0; mi < 4; ++mi)
        #pragma unroll
        for (int ni = 0; ni < 8; ++ni)
            acc[mi][ni] = (f32x4){0.f, 0.f, 0.f, 0.f};

    unsigned short* const Ap[3] = {A0, A1, A2};

    #pragma unroll 1
    for (int i = 0; i < 6; ++i) {
        int kh     = i >> 1;
        int cihalf = i & 1;

        // ---- stage (single-buffered; prev readers done at prev trailing barrier) ----
        // A: 3 half-planes x 2048 segs of 16B (12 segs/thread)
        #pragma unroll
        for (int p = 0; p < 3; ++p) {
            const unsigned short* wsrc = wr + (size_t)(kh * 3 + p) * (COUT * CIN) + cihalf * 64;
            unsigned short* dst = Ap[p];
            #pragma unroll
            for (int it = 0; it < 4; ++it) {
                int seg = it * 512 + t;
                int r   = seg >> 3;
                int s   = seg & 7;
                int c   = s ^ (r & 7);
                gload_lds16(wsrc + r * CIN + c * 8, &dst[seg * 8]);
            }
        }
        // B: cols 0..257 of padded row h+kh, this ci-half: 2064 segs (4/thread + tail)
        // new layout: global 16B unit = xrow + c*CHROW + col*8
        {
            const unsigned short* xrow = xb + (size_t)(h + kh) * ROWP + cihalf * 8 * CHROW;
            #pragma unroll
            for (int it = 0; it < 4; ++it) {
                int seg = it * 512 + t;
                int col = seg >> 3;
                int s   = seg & 7;
                int c   = s ^ (col & 7);
                gload_lds16(xrow + c * CHROW + col * 8, &Bs[col * 64 + s * 8]);
            }
            if (t < 16) {
                int seg = 2048 + t;           // cols 256, 257
                int col = seg >> 3;
                int s   = seg & 7;
                int c   = s ^ (col & 7);
                gload_lds16(xrow + c * CHROW + col * 8, &Bs[col * 64 + s * 8]);
            }
        }
        asm volatile("s_waitcnt vmcnt(0)" ::: "memory");
        __builtin_amdgcn_s_barrier();
        __builtin_amdgcn_sched_barrier(0);

        // ---- compute: barrier-free region, 2 K32-chunks ----
        #pragma unroll
        for (int kk = 0; kk < 2; ++kk) {
            int ck  = kk * 4 + quad;              // storage chunk 0..7 within ci-half
            int asl = (ck ^ (l16 & 7)) * 8;       // A slot offset (row&7 == l16&7)

            bf16x8 af0[4], af1[4], af2[4];
            #pragma unroll
            for (int mi = 0; mi < 4; ++mi) {
                int ro = (wm * 64 + mi * 16 + l16) * 64;
                af0[mi] = *(const bf16x8*)(&A0[ro + asl]);
                af1[mi] = *(const bf16x8*)(&A1[ro + asl]);
                af2[mi] = *(const bf16x8*)(&A2[ro + asl]);
            }

            // B fragment reader (halo cols >257 clamp to 257; those lanes unused)
            auto rdB = [&](int ni_) -> bf16x8 {
                int col = wn * 128 + ni_ * 16 + l16;
                if (col > 257) col = 257;
                return *(const bf16x8*)(&Bs[col * 64 + ((ck ^ (col & 7)) * 8)]);
            };

            bf16x8 cur = rdB(0);
            #pragma unroll
            for (int ni = 0; ni < 8; ++ni) {
                bf16x8 nxt = rdB(ni + 1);
                // kw=1 operand: col base+l16+1 ; lane15 takes next frag's lane0
                bf16x8 r1c = rotf<ROR_P1>(cur), r1n = rotf<ROR_P1>(nxt);
                bf16x8 s1  = (l16 == 15) ? r1n : r1c;
                // kw=2 operand: col base+l16+2 ; lanes14,15 take next frag's lanes0,1
                bf16x8 r2c = rotf<ROR_P2>(cur), r2n = rotf<ROR_P2>(nxt);
                bf16x8 s2  = (l16 >= 14) ? r2n : r2c;

                __builtin_amdgcn_s_setprio(1);
                #pragma unroll
                for (int mi = 0; mi < 4; ++mi)
                    acc[mi][ni] = __builtin_amdgcn_mfma_f32_16x16x32_bf16(
                        af0[mi], cur, acc[mi][ni], 0, 0, 0);
                #pragma unroll
                for (int mi = 0; mi < 4; ++mi)
                    acc[mi][ni] = __builtin_amdgcn_mfma_f32_16x16x32_bf16(
                        af1[mi], s1, acc[mi][ni], 0, 0, 0);
                #pragma unroll
                for (int mi = 0; mi < 4; ++mi)
                    acc[mi][ni] = __builtin_amdgcn_mfma_f32_16x16x32_bf16(
                        af2[mi], s2, acc[mi][ni], 0, 0, 0);
                __builtin_amdgcn_s_setprio(0);
                cur = nxt;
            }
        }
        // trailing barrier: all LDS reads consumed (compiler lgkm-waits before MFMA use)
        __builtin_amdgcn_s_barrier();
        __builtin_amdgcn_sched_barrier(0);
    }

    // epilogue: C/D layout col(spatial)=lane&15, row(co)=quad*4+reg
    int sp0 = wn * 128 + l16;
    #pragma unroll
    for (int mi = 0; mi < 4; ++mi) {
        #pragma unroll
        for (int r = 0; r < 4; ++r) {
            int co = wm * 64 + mi * 16 + quad * 4 + r;
            float b = bias[co];
            float* orow = out + (size_t)co * (HH * WW) + h * WW + sp0;
            #pragma unroll
            for (int ni = 0; ni < 8; ++ni)
                orow[ni * 16] = acc[mi][ni][r] + b;
        }
    }
}

extern "C" void kernel_launch(void* const* d_in, const int* in_sizes, int n_in,
                              void* d_out, int out_size, void* d_ws, size_t ws_size,
                              hipStream_t stream) {
    const float* x    = (const float*)d_in[0];   // [1,128,256,256]
    const float* w    = (const float*)d_in[1];   // [256,128,3,3]
    const float* bias = (const float*)d_in[2];   // [256]
    float* out        = (float*)d_out;           // [1,256,256,256]

    unsigned short* xb = (unsigned short*)d_ws;              // 258*258*128 bf16 = 17,040,384 B
    unsigned short* wr = xb + (size_t)HP * HP * CIN;         // 9*256*128 bf16  =    589,824 B

    prep_kernel<<<dim3(1024), dim3(256), 0, stream>>>(x, w, xb, wr);
    conv_mfma_kernel<<<dim3(256), dim3(512), 0, stream>>>(xb, wr, bias, out);
}

// Round 8
// 144.571 us; speedup vs baseline: 1.0404x; 1.0404x over previous
//
#include <hip/hip_runtime.h>
#include <hip/hip_bf16.h>

// Conv 3x3, C_IN=128, C_OUT=256, H=W=256, pad=1, stride=1, batch=1.
// R14 (resubmit; previous bench died with "container failed twice" -- infra, no verdict).
//   2 blocks/CU (cross-block overlap) x R12 rotate compute.
//   R13 post-mortem: xb re-layout scattered conv's B segments -> conv 67 us; prep's
//   write was never the residual (total-conv ~83 us invariant). Reverted.
//   R7..R12 evidence: intra-block scheduling nulls; serial-sum model fits ~51 us
//   (MFMA 18.6 + LDS ~12 + staging ~6 + rest). Only 2-blocks/CU overlapped phases
//   (R7, best conv 50.6 despite 36 phases + 2x staging).
//   Now: 512 blocks x 256 thr (4 waves), block = 128co x 256sp. LDS exactly 80 KB:
//   A 3x[128][64] (48 KB) + B [256][64] real cols only (32 KB) -> 2 blocks/CU.
//   Zero-pad cols 0/257 materialized in-register (lane-predicated zero in rdB).
//   Compute = R12's verified rotate path (B read once per K32 chunk; kw=1/2 by DPP
//   row_ror + next-frag patch; LDS reads 24 kcyc/CU << MFMA 44.7 kcyc).
//   One block's vmcnt(0)+barrier drain rides under the other block's MFMA.

typedef short bf16x8 __attribute__((ext_vector_type(8)));    // 8 bf16 = 4 VGPRs
typedef float f32x4 __attribute__((ext_vector_type(4)));
typedef int   i32x4 __attribute__((ext_vector_type(4)));
typedef unsigned short u16x4 __attribute__((ext_vector_type(4)));
typedef unsigned short u16x8 __attribute__((ext_vector_type(8)));

#define CIN   128
#define COUT  256
#define HH    256
#define WW    256
#define HP    258                 // padded
#define ROWP  (HP * CIN)          // padded row stride in elems = 33024

static __device__ __forceinline__ unsigned short f2bf(float v) {
    __hip_bfloat16 b = __float2bfloat16(v);
    return *reinterpret_cast<unsigned short*>(&b);
}

static __device__ __forceinline__ void gload_lds16(const unsigned short* g, unsigned short* l) {
    __builtin_amdgcn_global_load_lds(
        (const __attribute__((address_space(1))) unsigned int*)g,
        (__attribute__((address_space(3))) unsigned int*)l, 16, 0, 0);
}

// DPP rotate within each 16-lane row: row_ror:15 -> lane i <- lane i+1 ; ror:14 -> +2.
template<int CTRL>
static __device__ __forceinline__ bf16x8 rotf(bf16x8 a) {
    i32x4 ai = __builtin_bit_cast(i32x4, a);
    i32x4 r;
    #pragma unroll
    for (int j = 0; j < 4; ++j)
        r[j] = __builtin_amdgcn_mov_dpp(ai[j], CTRL, 0xF, 0xF, true);
    return __builtin_bit_cast(bf16x8, r);
}
#define ROR_P1 0x12F   // row_ror:15  (shift +1 lane)
#define ROR_P2 0x12E   // row_ror:14  (shift +2 lanes)

// ---------------- dispatch 1: fused prepass (edge zero + wreorder + xpose) -----------
// grid: 1024 blocks x 256 threads. xb layout: [hp][w][ci] (R12-verified original).
__global__ __launch_bounds__(256) void prep_kernel(const float* __restrict__ x,
                                                   const float* __restrict__ w,
                                                   unsigned short* __restrict__ xb,
                                                   unsigned short* __restrict__ wr) {
    int bid = blockIdx.x;
    int t   = threadIdx.x;

    // (a) edge zeroing: blocks 0..64 cover the 16448 vec8 border tasks
    //     (row zeroing hp=0,257 is REQUIRED for kh edges; col zeroing kept harmless)
    if (bid < 65) {
        int i = bid * 256 + t;
        if (i < 16448) {
            u16x8 z = {0, 0, 0, 0, 0, 0, 0, 0};
            int off;
            if (i < 8256) {
                int r   = (i >= 4128) ? 1 : 0;
                int rem = i - r * 4128;
                off = (r * 257) * ROWP + rem * 8;
            } else {
                int j   = i - 8256;           // 0..8191
                int col = j >> 12;            // 0 or 1
                int rem = j & 4095;
                int hp  = (rem >> 4) + 1;     // 1..256
                int c8  = rem & 15;
                off = hp * ROWP + (col * 257) * CIN + c8 * 8;
            }
            *(u16x8*)(&xb[off]) = z;
        }
    }

    // (b) weight reorder: blocks 0..127, one thread per (co,ci), coalesced
    if (bid < 128) {
        int p = bid * 256 + t;    // 0..32767 = co*128+ci
        const float* src = w + p * 9;
        #pragma unroll
        for (int khw = 0; khw < 9; ++khw)
            wr[khw * (COUT * CIN) + p] = f2bf(src[khw]);
    }

    // (c) xpose: NCHW fp32 -> padded NHWC bf16, one 64-w tile per block
    int h  = bid >> 2;
    int w0 = (bid & 3) * 64;
    __shared__ unsigned short tile[CIN * 72];   // [ci][w], w padded 64->72

    int wq  = t & 15;          // 16 * float4 = 64 w
    int cib = t >> 4;          // 16 ci per pass
    for (int c0 = 0; c0 < CIN; c0 += 16) {
        int ci = c0 + cib;
        float4 v = *(const float4*)(x + ci * (HH * WW) + h * WW + w0 + wq * 4);
        u16x4 p;
        p.x = f2bf(v.x); p.y = f2bf(v.y); p.z = f2bf(v.z); p.w = f2bf(v.w);
        *(u16x4*)(&tile[ci * 72 + wq * 4]) = p;
    }
    __syncthreads();

    for (int it = 0; it < 4; ++it) {
        int idx = it * 256 + t;       // 0..1023
        int ww_ = idx & 63;           // varies within wave (conflict-free LDS reads)
        int c8  = idx >> 6;           // 0..15, wave-uniform
        u16x8 o;
        #pragma unroll
        for (int j = 0; j < 8; ++j)
            o[j] = tile[(c8 * 8 + j) * 72 + ww_];
        int dst = ((h + 1) * HP + (w0 + ww_ + 1)) * CIN + c8 * 8;
        *(u16x8*)(&xb[dst]) = o;
    }
}

// ---------------- dispatch 2: implicit-GEMM MFMA conv, 2 blocks/CU -------------------
// 512 blocks x 256 thr (4 waves of 64co x 128sp). Block = 128co x 256sp (row h,
// co-half co0). LDS exactly 80 KB -> 2 blocks/CU; independent blocks' barriers
// desync -> one block's staging drain overlaps the other's MFMA.
// A planes [128 rows][64 ci]: 16B chunk c of row at slot c^(row&7).
// Bs [256 stored cols][64 ci]: stored col sc = padded col-1; chunk c at slot c^(sc&7).
__global__ __launch_bounds__(256, 2) void conv_mfma_kernel(const unsigned short* __restrict__ xb,
                                                           const unsigned short* __restrict__ wr,
                                                           const float* __restrict__ bias,
                                                           float* __restrict__ out) {
    __shared__ unsigned short A0[128 * 64];    // 16384 B  (kw=0)
    __shared__ unsigned short A1[128 * 64];    // 16384 B  (kw=1)
    __shared__ unsigned short A2[128 * 64];    // 16384 B  (kw=2)
    __shared__ unsigned short Bs[256 * 64];    // 32768 B  ; total 81920 B = 80 KB

    // XCD-chunked bijective swizzle: 512 blocks, 8 XCDs -> 32 h-rows x 2 co-halves
    // per XCD; the two co-halves of one h are dispatched adjacently (share B in L2).
    int bid   = blockIdx.x;
    int inner = bid >> 3;                      // 0..63
    int h     = (bid & 7) * 32 + (inner >> 1); // 0..255
    int co0   = (inner & 1) * 128;             // co-half

    int t    = threadIdx.x;     // 0..255
    int lane = t & 63;
    int wave = t >> 6;          // 0..3
    int wm   = wave >> 1;       // co quarter within block (0/1), 64 co each
    int wn   = wave & 1;        // spatial half (0/1), 128 sp each
    int quad = lane >> 4;
    int l16  = lane & 15;

    f32x4 acc[4][8];
    #pragma unroll
    for (int mi = 0; mi < 4; ++mi)
        #pragma unroll
        for (int ni = 0; ni < 8; ++ni)
            acc[mi][ni] = (f32x4){0.f, 0.f, 0.f, 0.f};

    unsigned short* const Ap[3] = {A0, A1, A2};

    #pragma unroll 1
    for (int i = 0; i < 6; ++i) {
        int kh     = i >> 1;
        int cihalf = i & 1;

        // ---- stage (single-buffered; prev readers done at prev trailing barrier) ----
        // A: 3 planes x 1024 segs of 16B (4 segs/thread each)
        #pragma unroll
        for (int p = 0; p < 3; ++p) {
            const unsigned short* wsrc =
                wr + (size_t)(kh * 3 + p) * (COUT * CIN) + co0 * CIN + cihalf * 64;
            unsigned short* dst = Ap[p];
            #pragma unroll
            for (int it = 0; it < 4; ++it) {
                int seg = it * 256 + t;
                int r   = seg >> 3;
                int s   = seg & 7;
                int c   = s ^ (r & 7);
                gload_lds16(wsrc + r * CIN + c * 8, &dst[seg * 8]);
            }
        }
        // B: real padded cols 1..256 -> stored cols 0..255: 2048 segs (8/thread)
        {
            const unsigned short* xrow = xb + (size_t)(h + kh) * ROWP + cihalf * 64;
            #pragma unroll
            for (int it = 0; it < 8; ++it) {
                int seg = it * 256 + t;
                int sc  = seg >> 3;
                int s   = seg & 7;
                int c   = s ^ (sc & 7);
                gload_lds16(xrow + (sc + 1) * CIN + c * 8, &Bs[seg * 8]);
            }
        }
        asm volatile("s_waitcnt vmcnt(0)" ::: "memory");
        __builtin_amdgcn_s_barrier();
        __builtin_amdgcn_sched_barrier(0);

        // ---- compute: barrier-free region, 2 K32-chunks (R12-verified rotate path) ----
        #pragma unroll
        for (int kk = 0; kk < 2; ++kk) {
            int ck  = kk * 4 + quad;              // storage chunk 0..7 within ci-half
            int asl = (ck ^ (l16 & 7)) * 8;       // A slot offset (row&7 == l16&7)

            bf16x8 af0[4], af1[4], af2[4];
            #pragma unroll
            for (int mi = 0; mi < 4; ++mi) {
                int ro = (wm * 64 + mi * 16 + l16) * 64;
                af0[mi] = *(const bf16x8*)(&A0[ro + asl]);
                af1[mi] = *(const bf16x8*)(&A1[ro + asl]);
                af2[mi] = *(const bf16x8*)(&A2[ro + asl]);
            }

            // B fragment reader in PADDED col space; pad cols (0, >=257) -> zero frag.
            auto rdB = [&](int ni_) -> bf16x8 {
                int pc  = wn * 128 + ni_ * 16 + l16;   // padded col for kw=0 operand
                int sc  = pc - 1;
                int scc = sc < 0 ? 0 : (sc > 255 ? 255 : sc);
                bf16x8 v = *(const bf16x8*)(&Bs[scc * 64 + ((ck ^ (scc & 7)) * 8)]);
                if (pc < 1 || pc > 256) {
                    bf16x8 z = {0, 0, 0, 0, 0, 0, 0, 0};
                    v = z;
                }
                return v;
            };

            bf16x8 cur = rdB(0);
            #pragma unroll
            for (int ni = 0; ni < 8; ++ni) {
                bf16x8 nxt = rdB(ni + 1);
                // kw=1 operand: col base+l16+1 ; lane15 takes next frag's lane0
                bf16x8 r1c = rotf<ROR_P1>(cur), r1n = rotf<ROR_P1>(nxt);
                bf16x8 s1  = (l16 == 15) ? r1n : r1c;
                // kw=2 operand: col base+l16+2 ; lanes14,15 take next frag's lanes0,1
                bf16x8 r2c = rotf<ROR_P2>(cur), r2n = rotf<ROR_P2>(nxt);
                bf16x8 s2  = (l16 >= 14) ? r2n : r2c;

                __builtin_amdgcn_s_setprio(1);
                #pragma unroll
                for (int mi = 0; mi < 4; ++mi)
                    acc[mi][ni] = __builtin_amdgcn_mfma_f32_16x16x32_bf16(
                        af0[mi], cur, acc[mi][ni], 0, 0, 0);
                #pragma unroll
                for (int mi = 0; mi < 4; ++mi)
                    acc[mi][ni] = __builtin_amdgcn_mfma_f32_16x16x32_bf16(
                        af1[mi], s1, acc[mi][ni], 0, 0, 0);
                #pragma unroll
                for (int mi = 0; mi < 4; ++mi)
                    acc[mi][ni] = __builtin_amdgcn_mfma_f32_16x16x32_bf16(
                        af2[mi], s2, acc[mi][ni], 0, 0, 0);
                __builtin_amdgcn_s_setprio(0);
                cur = nxt;
            }
        }
        // trailing barrier: all LDS reads consumed (compiler lgkm-waits before MFMA use)
        __builtin_amdgcn_s_barrier();
        __builtin_amdgcn_sched_barrier(0);
    }

    // epilogue: C/D layout col(spatial)=lane&15, row(co)=quad*4+reg
    int sp0 = wn * 128 + l16;
    #pragma unroll
    for (int mi = 0; mi < 4; ++mi) {
        #pragma unroll
        for (int r = 0; r < 4; ++r) {
            int co = co0 + wm * 64 + mi * 16 + quad * 4 + r;
            float b = bias[co];
            float* orow = out + (size_t)co * (HH * WW) + h * WW + sp0;
            #pragma unroll
            for (int ni = 0; ni < 8; ++ni)
                orow[ni * 16] = acc[mi][ni][r] + b;
        }
    }
}

extern "C" void kernel_launch(void* const* d_in, const int* in_sizes, int n_in,
                              void* d_out, int out_size, void* d_ws, size_t ws_size,
                              hipStream_t stream) {
    const float* x    = (const float*)d_in[0];   // [1,128,256,256]
    const float* w    = (const float*)d_in[1];   // [256,128,3,3]
    const float* bias = (const float*)d_in[2];   // [256]
    float* out        = (float*)d_out;           // [1,256,256,256]

    unsigned short* xb = (unsigned short*)d_ws;              // 258*258*128 bf16 = 17,040,384 B
    unsigned short* wr = xb + (size_t)HP * HP * CIN;         // 9*256*128 bf16  =    589,824 B

    prep_kernel<<<dim3(1024), dim3(256), 0, stream>>>(x, w, xb, wr);
    conv_mfma_kernel<<<dim3(512), dim3(256), 0, stream>>>(xb, wr, bias, out);
}

// Round 9
// 139.471 us; speedup vs baseline: 1.0784x; 1.0366x over previous
//
#include <hip/hip_runtime.h>
#include <hip/hip_bf16.h>

// Conv 3x3, C_IN=128, C_OUT=256, H=W=256, pad=1, stride=1, batch=1.
// R15: occupancy x4 -- 4 blocks/CU, 16 waves/CU (4/SIMD).
//   R14 post-mortem: 2 blocks/CU = 8 waves/CU, SAME occupancy as 1x512 (16.5%);
//   regressed via redundant B staging. Across R7-R14 every config ran 2 waves/SIMD;
//   pipe sums (Mfma 27 + VALU 20 + LDS ~10) say >40% of cycles NOTHING issues --
//   latency-bound at 2 waves/SIMD, and wave count was never varied.
//   Now: 1024 blocks x 256 thr (4 waves), block = 128co x 128sp of one h row.
//   LDS 32.9 KB: A 3x[128 rows][32 ci] (24 KB) + B [130 cols][32 ci] (8.3 KB)
//   -> 4 blocks/CU. 12 iters (3 kh x 4 ci-quarters), one K32 step per iter.
//   Wave = 32co x 128sp: acc[2][8]=64 VGPR, af 6x4=24 -> fits 128 (launch_bounds 256,4).
//   Compute = R12-verified rotate path (B read once; kw=1/2 via DPP row_ror +
//   next-frag patch; pad cols are real zeroed xb data -> no predication).
//   4-slot XOR c^((idx>>1)&3) keeps A/B reads 2-way (free) on 64 B rows.
//   4 desynced blocks: one block's stage+vmcnt(0) drain rides under others' MFMA.

typedef short bf16x8 __attribute__((ext_vector_type(8)));    // 8 bf16 = 4 VGPRs
typedef float f32x4 __attribute__((ext_vector_type(4)));
typedef int   i32x4 __attribute__((ext_vector_type(4)));
typedef unsigned short u16x4 __attribute__((ext_vector_type(4)));
typedef unsigned short u16x8 __attribute__((ext_vector_type(8)));

#define CIN   128
#define COUT  256
#define HH    256
#define WW    256
#define HP    258                 // padded
#define ROWP  (HP * CIN)          // padded row stride in elems = 33024

static __device__ __forceinline__ unsigned short f2bf(float v) {
    __hip_bfloat16 b = __float2bfloat16(v);
    return *reinterpret_cast<unsigned short*>(&b);
}

static __device__ __forceinline__ void gload_lds16(const unsigned short* g, unsigned short* l) {
    __builtin_amdgcn_global_load_lds(
        (const __attribute__((address_space(1))) unsigned int*)g,
        (__attribute__((address_space(3))) unsigned int*)l, 16, 0, 0);
}

// DPP rotate within each 16-lane row: row_ror:15 -> lane i <- lane i+1 ; ror:14 -> +2.
template<int CTRL>
static __device__ __forceinline__ bf16x8 rotf(bf16x8 a) {
    i32x4 ai = __builtin_bit_cast(i32x4, a);
    i32x4 r;
    #pragma unroll
    for (int j = 0; j < 4; ++j)
        r[j] = __builtin_amdgcn_mov_dpp(ai[j], CTRL, 0xF, 0xF, true);
    return __builtin_bit_cast(bf16x8, r);
}
#define ROR_P1 0x12F   // row_ror:15  (shift +1 lane)
#define ROR_P2 0x12E   // row_ror:14  (shift +2 lanes)

// ---------------- dispatch 1: fused prepass (edge zero + wreorder + xpose) -----------
// grid: 1024 blocks x 256 threads. xb layout: [hp][w][ci] (verified original).
__global__ __launch_bounds__(256) void prep_kernel(const float* __restrict__ x,
                                                   const float* __restrict__ w,
                                                   unsigned short* __restrict__ xb,
                                                   unsigned short* __restrict__ wr) {
    int bid = blockIdx.x;
    int t   = threadIdx.x;

    // (a) edge zeroing: blocks 0..64 cover the 16448 vec8 border tasks
    if (bid < 65) {
        int i = bid * 256 + t;
        if (i < 16448) {
            u16x8 z = {0, 0, 0, 0, 0, 0, 0, 0};
            int off;
            if (i < 8256) {
                int r   = (i >= 4128) ? 1 : 0;
                int rem = i - r * 4128;
                off = (r * 257) * ROWP + rem * 8;
            } else {
                int j   = i - 8256;           // 0..8191
                int col = j >> 12;            // 0 or 1
                int rem = j & 4095;
                int hp  = (rem >> 4) + 1;     // 1..256
                int c8  = rem & 15;
                off = hp * ROWP + (col * 257) * CIN + c8 * 8;
            }
            *(u16x8*)(&xb[off]) = z;
        }
    }

    // (b) weight reorder: blocks 0..127, one thread per (co,ci), coalesced
    if (bid < 128) {
        int p = bid * 256 + t;    // 0..32767 = co*128+ci
        const float* src = w + p * 9;
        #pragma unroll
        for (int khw = 0; khw < 9; ++khw)
            wr[khw * (COUT * CIN) + p] = f2bf(src[khw]);
    }

    // (c) xpose: NCHW fp32 -> padded NHWC bf16, one 64-w tile per block
    int h  = bid >> 2;
    int w0 = (bid & 3) * 64;
    __shared__ unsigned short tile[CIN * 72];   // [ci][w], w padded 64->72

    int wq  = t & 15;          // 16 * float4 = 64 w
    int cib = t >> 4;          // 16 ci per pass
    for (int c0 = 0; c0 < CIN; c0 += 16) {
        int ci = c0 + cib;
        float4 v = *(const float4*)(x + ci * (HH * WW) + h * WW + w0 + wq * 4);
        u16x4 p;
        p.x = f2bf(v.x); p.y = f2bf(v.y); p.z = f2bf(v.z); p.w = f2bf(v.w);
        *(u16x4*)(&tile[ci * 72 + wq * 4]) = p;
    }
    __syncthreads();

    for (int it = 0; it < 4; ++it) {
        int idx = it * 256 + t;       // 0..1023
        int ww_ = idx & 63;           // varies within wave (conflict-free LDS reads)
        int c8  = idx >> 6;           // 0..15, wave-uniform
        u16x8 o;
        #pragma unroll
        for (int j = 0; j < 8; ++j)
            o[j] = tile[(c8 * 8 + j) * 72 + ww_];
        int dst = ((h + 1) * HP + (w0 + ww_ + 1)) * CIN + c8 * 8;
        *(u16x8*)(&xb[dst]) = o;
    }
}

// ---------------- dispatch 2: implicit-GEMM MFMA conv, 4 blocks/CU -------------------
// 1024 blocks x 256 thr (4 waves of 32co x 128sp). Block = 128co x 128sp of one h row.
// LDS 32.9 KB -> 4 blocks/CU, 16 waves/CU. 12 iters: (kh 0..2) x (ci-quarter 0..3),
// each = one K32 MFMA step. A planes [128 rows][32 ci]: chunk c of row r at slot
// c^((r>>1)&3). Bs [130 local cols][32 ci]: chunk c of col lc at slot c^((lc>>1)&3);
// local col lc = padded col - s0 (pad cols 0/257 hold real zeros from prep).
__global__ __launch_bounds__(256, 4) void conv_mfma_kernel(const unsigned short* __restrict__ xb,
                                                           const unsigned short* __restrict__ wr,
                                                           const float* __restrict__ bias,
                                                           float* __restrict__ out) {
    __shared__ unsigned short A0[128 * 32];    // 8192 B  (kw=0)
    __shared__ unsigned short A1[128 * 32];    // 8192 B  (kw=1)
    __shared__ unsigned short A2[128 * 32];    // 8192 B  (kw=2)
    __shared__ unsigned short Bs[130 * 32];    // 8320 B  ; total 32896 B

    // XCD-chunked bijective swizzle: 1024 blocks, 8 XCDs -> 128 per XCD;
    // the 4 quadrants (2co x 2sp) of one h are adjacent -> share xb row / wr in L2.
    int bid   = blockIdx.x;
    int inner = bid >> 3;                       // 0..127
    int h     = (bid & 7) * 32 + (inner >> 2);  // 0..255
    int co0   = (inner & 1) * 128;              // co half
    int s0    = ((inner >> 1) & 1) * 128;       // spatial half

    int t    = threadIdx.x;     // 0..255
    int lane = t & 63;
    int wave = t >> 6;          // 0..3 -> co sub-block (32 co each)
    int quad = lane >> 4;
    int l16  = lane & 15;

    f32x4 acc[2][8];
    #pragma unroll
    for (int mi = 0; mi < 2; ++mi)
        #pragma unroll
        for (int ni = 0; ni < 8; ++ni)
            acc[mi][ni] = (f32x4){0.f, 0.f, 0.f, 0.f};

    #pragma unroll 1
    for (int i = 0; i < 12; ++i) {
        int kh  = i >> 2;
        int ciq = i & 3;

        // ---- stage (single-buffered; prev readers done at prev trailing barrier) ----
        // A: 3 planes x 512 segs of 16B (2 segs/thread each)
        {
            const unsigned short* wbase =
                wr + (size_t)(kh * 3) * (COUT * CIN) + co0 * CIN + ciq * 32;
            #pragma unroll
            for (int it = 0; it < 2; ++it) {
                int seg = it * 256 + t;           // 0..511
                int r   = seg >> 2;
                int s   = seg & 3;
                int c   = s ^ ((r >> 1) & 3);
                const unsigned short* src = wbase + r * CIN + c * 8;
                gload_lds16(src,                    &A0[seg * 8]);
                gload_lds16(src + (COUT * CIN),     &A1[seg * 8]);
                gload_lds16(src + 2 * (COUT * CIN), &A2[seg * 8]);
            }
        }
        // B: 130 local cols x 4 slots = 520 segs (2/thread + 8 tail)
        {
            const unsigned short* xrow = xb + (size_t)(h + kh) * ROWP + ciq * 32;
            #pragma unroll
            for (int it = 0; it < 2; ++it) {
                int seg = it * 256 + t;           // 0..511
                int lc  = seg >> 2;
                int s   = seg & 3;
                int c   = s ^ ((lc >> 1) & 3);
                gload_lds16(xrow + (s0 + lc) * CIN + c * 8, &Bs[seg * 8]);
            }
            if (t < 8) {
                int seg = 512 + t;                // lc 128,129
                int lc  = seg >> 2;
                int s   = seg & 3;
                int c   = s ^ ((lc >> 1) & 3);
                gload_lds16(xrow + (s0 + lc) * CIN + c * 8, &Bs[seg * 8]);
            }
        }
        asm volatile("s_waitcnt vmcnt(0)" ::: "memory");
        __builtin_amdgcn_s_barrier();
        __builtin_amdgcn_sched_barrier(0);

        // ---- compute: one K32 step (chunk = quad within this ci-quarter) ----
        {
            int ck = quad;

            bf16x8 af0[2], af1[2], af2[2];
            #pragma unroll
            for (int mi = 0; mi < 2; ++mi) {
                int row = wave * 32 + mi * 16 + l16;
                int ro  = row * 32 + (ck ^ ((row >> 1) & 3)) * 8;
                af0[mi] = *(const bf16x8*)(&A0[ro]);
                af1[mi] = *(const bf16x8*)(&A1[ro]);
                af2[mi] = *(const bf16x8*)(&A2[ro]);
            }

            // B fragment reader, local padded-col space (halo lanes clamp to 129)
            auto rdB = [&](int ni_) -> bf16x8 {
                int lc = ni_ * 16 + l16;
                if (lc > 129) lc = 129;
                return *(const bf16x8*)(&Bs[lc * 32 + ((ck ^ ((lc >> 1) & 3)) * 8)]);
            };

            bf16x8 cur = rdB(0);
            #pragma unroll
            for (int ni = 0; ni < 8; ++ni) {
                bf16x8 nxt = rdB(ni + 1);
                // kw=1 operand: col +1 ; lane15 takes next frag's lane0
                bf16x8 r1c = rotf<ROR_P1>(cur), r1n = rotf<ROR_P1>(nxt);
                bf16x8 s1  = (l16 == 15) ? r1n : r1c;
                // kw=2 operand: col +2 ; lanes14,15 take next frag's lanes0,1
                bf16x8 r2c = rotf<ROR_P2>(cur), r2n = rotf<ROR_P2>(nxt);
                bf16x8 s2  = (l16 >= 14) ? r2n : r2c;

                __builtin_amdgcn_s_setprio(1);
                #pragma unroll
                for (int mi = 0; mi < 2; ++mi)
                    acc[mi][ni] = __builtin_amdgcn_mfma_f32_16x16x32_bf16(
                        af0[mi], cur, acc[mi][ni], 0, 0, 0);
                #pragma unroll
                for (int mi = 0; mi < 2; ++mi)
                    acc[mi][ni] = __builtin_amdgcn_mfma_f32_16x16x32_bf16(
                        af1[mi], s1, acc[mi][ni], 0, 0, 0);
                #pragma unroll
                for (int mi = 0; mi < 2; ++mi)
                    acc[mi][ni] = __builtin_amdgcn_mfma_f32_16x16x32_bf16(
                        af2[mi], s2, acc[mi][ni], 0, 0, 0);
                __builtin_amdgcn_s_setprio(0);
                cur = nxt;
            }
        }
        // trailing barrier: all LDS reads consumed (compiler lgkm-waits before MFMA use)
        __builtin_amdgcn_s_barrier();
        __builtin_amdgcn_sched_barrier(0);
    }

    // epilogue: C/D layout col(spatial)=lane&15, row(co)=quad*4+reg
    #pragma unroll
    for (int mi = 0; mi < 2; ++mi) {
        #pragma unroll
        for (int r = 0; r < 4; ++r) {
            int co = co0 + wave * 32 + mi * 16 + quad * 4 + r;
            float b = bias[co];
            float* orow = out + (size_t)co * (HH * WW) + h * WW + s0 + l16;
            #pragma unroll
            for (int ni = 0; ni < 8; ++ni)
                orow[ni * 16] = acc[mi][ni][r] + b;
        }
    }
}

extern "C" void kernel_launch(void* const* d_in, const int* in_sizes, int n_in,
                              void* d_out, int out_size, void* d_ws, size_t ws_size,
                              hipStream_t stream) {
    const float* x    = (const float*)d_in[0];   // [1,128,256,256]
    const float* w    = (const float*)d_in[1];   // [256,128,3,3]
    const float* bias = (const float*)d_in[2];   // [256]
    float* out        = (float*)d_out;           // [1,256,256,256]

    unsigned short* xb = (unsigned short*)d_ws;              // 258*258*128 bf16 = 17,040,384 B
    unsigned short* wr = xb + (size_t)HP * HP * CIN;         // 9*256*128 bf16  =    589,824 B

    prep_kernel<<<dim3(1024), dim3(256), 0, stream>>>(x, w, xb, wr);
    conv_mfma_kernel<<<dim3(1024), dim3(256), 0, stream>>>(xb, wr, bias, out);
}